// Round 12
// baseline (575.354 us; speedup 1.0000x reference)
//
#include <hip/hip_runtime.h>
#include <hip/hip_bf16.h>
#include <stdint.h>

#define NEXP 8
#define DM   1024
#define HID  4096
#define NTOK 8192
#define CAPS 2048   // expert capacity = K*ceil(N/E) = 2*1024

#define BM 256
#define BN 128
#define BK 32

typedef __attribute__((ext_vector_type(8))) short bh8_t;
typedef __attribute__((ext_vector_type(4))) float f32x4_t;
typedef unsigned short u16;

static __device__ __forceinline__ u16 f2bf(float f) {
    __hip_bfloat16 h = __float2bfloat16(f);
    return __builtin_bit_cast(u16, h);
}
static __device__ __forceinline__ float bf2f(u16 u) {
    unsigned int x = ((unsigned int)u) << 16;
    return __builtin_bit_cast(float, x);
}

#define FENCE asm volatile("" ::: "memory")
#define BAR   do { FENCE; __builtin_amdgcn_s_barrier(); FENCE; } while (0)
#define MFMA(d, a, b) d = __builtin_amdgcn_mfma_f32_16x16x32_bf16(a, b, d, 0, 0, 0)
#define WAITVM(n) do { if ((n) == 3) asm volatile("s_waitcnt vmcnt(3)" ::: "memory"); \
    else if ((n) == 0) asm volatile("s_waitcnt vmcnt(0)" ::: "memory"); } while (0)
#define GLD(p, d) __builtin_amdgcn_global_load_lds( \
    (const __attribute__((address_space(1))) void*)(p), \
    (__attribute__((address_space(3))) void*)(d), 16, 0, 0)

// ---------------- fp32 -> bf16 elementwise convert (fc1 weights) ----------------
__global__ __launch_bounds__(256) void k_conv_bf16(const float* __restrict__ in,
                                                   u16* __restrict__ out, long n4) {
    long stride = (long)gridDim.x * 256;
    for (long i = (long)blockIdx.x * 256 + threadIdx.x; i < n4; i += stride) {
        float4 v = ((const float4*)in)[i];
        ushort4 o;
        o.x = f2bf(v.x); o.y = f2bf(v.y); o.z = f2bf(v.z); o.w = f2bf(v.w);
        ((ushort4*)out)[i] = o;
    }
}

// ---------------- fc2 [E,H,D] f32 -> [E,D,H] bf16 transpose (64x64 tiles) --------
__global__ __launch_bounds__(256) void k_transpose_w2(const float* __restrict__ in,
                                                      u16* __restrict__ out) {
    int e = blockIdx.z;
    const float* I = in + (long)e * HID * DM;
    u16* O = out + (long)e * DM * HID;
    __shared__ float t[64][65];
    int h0 = blockIdx.x * 64, d0 = blockIdx.y * 64;
    int tid = threadIdx.x;
    int r = tid >> 4, cw = (tid & 15) * 4;
    #pragma unroll
    for (int i = 0; i < 4; ++i) {
        float4 v = *(const float4*)(I + (long)(h0 + r + 16*i) * DM + d0 + cw);
        t[r + 16*i][cw]     = v.x;
        t[r + 16*i][cw + 1] = v.y;
        t[r + 16*i][cw + 2] = v.z;
        t[r + 16*i][cw + 3] = v.w;
    }
    __syncthreads();
    int dl = tid >> 2, hc = (tid & 3) * 16;
    bh8_t w0, w1;
    #pragma unroll
    for (int j = 0; j < 8; ++j) w0[j] = (short)f2bf(t[hc + j][dl]);
    #pragma unroll
    for (int j = 0; j < 8; ++j) w1[j] = (short)f2bf(t[hc + 8 + j][dl]);
    u16* o = O + (long)(d0 + dl) * HID + h0 + hc;
    *(bh8_t*)o = w0;
    *(bh8_t*)(o + 8) = w1;
}

// ---------------- gating: logits, softmax, top-2, normalized gates ----------------
__global__ __launch_bounds__(256) void k_gating(const float* __restrict__ x,
        const float* __restrict__ gw, int* __restrict__ topi, float* __restrict__ gates) {
    __shared__ float sg[NEXP][DM];   // 32 KB
    int tid = threadIdx.x;
    for (int i = tid; i < NEXP*DM; i += 256) ((float*)sg)[i] = gw[i];
    __syncthreads();
    int lane = tid & 63, w = tid >> 6;
    long n = (long)blockIdx.x * 4 + w;            // one token per wave
    const float* xr = x + n * DM;
    float acc[NEXP] = {};
    for (int i = 0; i < DM/64; ++i) {
        float xv = xr[lane + i*64];
        #pragma unroll
        for (int e = 0; e < NEXP; ++e) acc[e] += xv * sg[e][lane + i*64];
    }
    #pragma unroll
    for (int e = 0; e < NEXP; ++e)
        #pragma unroll
        for (int off = 32; off; off >>= 1) acc[e] += __shfl_xor(acc[e], off);
    if (lane == 0) {
        float mx = acc[0];
        #pragma unroll
        for (int e = 1; e < NEXP; ++e) mx = fmaxf(mx, acc[e]);
        float p[NEXP];
        #pragma unroll
        for (int e = 0; e < NEXP; ++e) p[e] = expf(acc[e] - mx);
        float v0 = p[0]; int i0 = 0;
        #pragma unroll
        for (int e = 1; e < NEXP; ++e) if (p[e] > v0) { v0 = p[e]; i0 = e; }
        float v1 = -1.f; int i1 = 0;
        #pragma unroll
        for (int e = 0; e < NEXP; ++e) if (e != i0 && p[e] > v1) { v1 = p[e]; i1 = e; }
        float tot = v0 + v1;
        topi[n*2]   = i0; topi[n*2+1] = i1;
        gates[n*2]  = v0 / tot; gates[n*2+1] = v1 / tot;
    }
}

// ---- capacity locations: exact sequential cumsum; ONE BLOCK PER EXPERT (8x) ----
__global__ __launch_bounds__(256) void k_locate(const int* __restrict__ topi,
                                                int* __restrict__ flat) {
    __shared__ int st[NTOK * 2];    // 64 KB staged topi
    __shared__ int wsum[4];
    int e = blockIdx.x;
    int tid = threadIdx.x, lane = tid & 63, w = tid >> 6;
    int4* st4 = (int4*)st;
    const int4* g4 = (const int4*)topi;
    for (int i = tid; i < NTOK * 2 / 4; i += 256) st4[i] = g4[i];
    __syncthreads();
    const int TPL = NTOK / 256;     // 32 consecutive tokens per thread
    int base = tid * TPL;
    int offset = 0;
    for (int j = 0; j < 2; ++j) {
        int cnt = 0;
        for (int t = 0; t < TPL; ++t) cnt += (st[(base + t) * 2 + j] == e);
        int v = cnt;
        #pragma unroll
        for (int d = 1; d < 64; d <<= 1) {
            int o = __shfl_up(v, d);
            if (lane >= d) v += o;
        }
        if (lane == 63) wsum[w] = v;
        __syncthreads();
        int wb = 0;
        #pragma unroll
        for (int ww = 0; ww < 4; ++ww) if (ww < w) wb += wsum[ww];
        int tot = wsum[0] + wsum[1] + wsum[2] + wsum[3];
        int loc = v - cnt + wb + offset;
        offset += tot;
        for (int t = 0; t < TPL; ++t) {
            int n = base + t;
            if (st[n * 2 + j] == e) {
                flat[n * 2 + j] = (loc < CAPS) ? (e * CAPS + loc) : -1;
                ++loc;
            }
        }
        __syncthreads();
    }
}

// ---------------- dispatch: scatter tokens (bf16) into [E*cap, D] ----------------
__global__ __launch_bounds__(256) void k_dispatch(const float* __restrict__ x,
        const int* __restrict__ flat, u16* __restrict__ disp) {
    long n = blockIdx.x;
    int tid = threadIdx.x;
    float4 v = *(const float4*)(x + n*DM + tid*4);
    ushort4 o; o.x = f2bf(v.x); o.y = f2bf(v.y); o.z = f2bf(v.z); o.w = f2bf(v.w);
    int f0 = flat[n*2], f1 = flat[n*2+1];
    if (f0 >= 0) *(ushort4*)(disp + (long)f0*DM + tid*4) = o;
    if (f1 >= 0) *(ushort4*)(disp + (long)f1*DM + tid*4) = o;
}

// ---------------- 256x128 BK=32 2-blocks/CU bf16 MFMA GEMM ----------------------
// C[M,N] = A[M,K]*B[N,K]^T + bias. 8 waves, each owns a 64x64 output (wr in [0,4),
// wc in [0,2)). LDS 48KB (2buf x (A 256x32 + B 128x32)) -> 2 blocks/CU; acc 64
// VGPR -> 4 waves/SIMD: cross-block overlap hides barrier/vmcnt stalls (m114).
// [row][32] swizzle (64B rows): store col c^((row>>1)&3), read fcs below -> 2-way.
// 2 barriers/tile: region1 = all 8 ds_reads + stage kt+1 -> c^1 + 8 MFMA;
// BAR; region2 = stage kt+2 -> c + 8 MFMA + vmcnt(3) + BAR. 3 loads/tile-stage:
// exit vmcnt(3) forces kt+1, leaves kt+2 in flight.
template<int RELU>
__global__ __launch_bounds__(512, 4)
void k_gemm8(const u16* __restrict__ A, const u16* __restrict__ B,
             const float* __restrict__ bias, u16* __restrict__ C,
             int N, int K, long strA, long strB, long strBias, long strC)
{
    __shared__ u16 sm[2][12288];   // [buf][A:0..8191 | B:8192..12287] = 48 KiB

    // T1: XCD-aware bijective remap (nwg % 8 == 0 for our grids)
    int gx = gridDim.x, gy = gridDim.y;
    int nwg = gx * gy * (int)gridDim.z;
    int lin = blockIdx.x + gx * (blockIdx.y + gy * blockIdx.z);
    int qq  = nwg >> 3;
    int swz = (lin & 7) * qq + (lin >> 3);
    int gxy = gx * gy;
    int bz = swz / gxy, rm = swz % gxy, by = rm / gx, bx = rm % gx;

    const float* bi = bias + (long)bz * strBias;
    u16* Ce = C + (long)bz * strC;

    long tm = (long)by * BM, tn = (long)bx * BN;
    const u16* Abase = A + (long)bz * strA + tm * (long)K;
    const u16* Bbase = B + (long)bz * strB + tn * (long)K;

    int tid = threadIdx.x, lane = tid & 63, wid = tid >> 6;
    int wr = wid >> 1, wc = wid & 1;            // 4x2 waves; per-wave 64x64 output

    int frow = lane & 15;
    // swizzled read chunk: src chunk (lane>>4) lives at LDS chunk (lane>>4)^((frow>>1)&3)
    int fcs = (((lane >> 4) ^ ((frow >> 1) & 3)) * 8);

    // staging: thread t covers LDS chunk (t&3) of row (t>>2); source col pre-swizzled
    int srow = tid >> 2;
    int scol = ((tid & 3) ^ ((tid >> 3) & 3)) * 8;
    int sdst = tid * 8;

    const int NT = K / BK;

    f32x4_t acc[4][4] = {};

    auto STGA = [&](int buf, int kt) {      // 2 loads: 256 rows x 32 cols
        const u16* g = Abase + (long)kt * BK + (long)srow * K + scol;
        u16* R = &sm[buf][0] + sdst;
        GLD(g, R);
        GLD(g + 128L * K, R + 4096);
    };
    auto STGB = [&](int buf, int kt) {      // 1 load: 128 rows x 32 cols
        const u16* g = Bbase + (long)kt * BK + (long)srow * K + scol;
        GLD(g, &sm[buf][8192] + sdst);
    };
    auto LDA = [&](int c, int mi) -> bh8_t {
        return *(const bh8_t*)(&sm[c][0] + (wr * 64 + mi * 16 + frow) * 32 + fcs);
    };
    auto LDB = [&](int c, int ni) -> bh8_t {
        return *(const bh8_t*)(&sm[c][8192] + (wc * 64 + ni * 16 + frow) * 32 + fcs);
    };

    auto ktile = [&](int c, int kt, int s1, int s2, int vmexit) {
        bh8_t a[4], b[4];
        // ---- region 1: all reads from buf c; stage kt+1 -> c^1; MFMA ni 0,1
        #pragma unroll
        for (int mi = 0; mi < 4; ++mi) a[mi] = LDA(c, mi);
        #pragma unroll
        for (int ni = 0; ni < 4; ++ni) b[ni] = LDB(c, ni);
        if (s1) { STGB(c ^ 1, kt + 1); STGA(c ^ 1, kt + 1); }
        __builtin_amdgcn_s_setprio(1);
        #pragma unroll
        for (int mi = 0; mi < 4; ++mi)
            #pragma unroll
            for (int ni = 0; ni < 2; ++ni) MFMA(acc[mi][ni], a[mi], b[ni]);
        __builtin_amdgcn_s_setprio(0);
        BAR;   // all c-reads done across waves -> region 2 may overwrite c
        // ---- region 2: stage kt+2 -> c; MFMA ni 2,3; exit wait
        if (s2) { STGB(c, kt + 2); STGA(c, kt + 2); }
        __builtin_amdgcn_s_setprio(1);
        #pragma unroll
        for (int mi = 0; mi < 4; ++mi)
            #pragma unroll
            for (int ni = 2; ni < 4; ++ni) MFMA(acc[mi][ni], a[mi], b[ni]);
        __builtin_amdgcn_s_setprio(0);
        WAITVM(vmexit);
        BAR;   // tile handoff
    };

    // prologue: kt0 (3 loads), kt1 (3 loads); vmcnt(3) forces kt0, leaves kt1 in flight
    STGB(0, 0); STGA(0, 0);
    STGB(1, 1); STGA(1, 1);
    asm volatile("s_waitcnt vmcnt(3)" ::: "memory");
    BAR;

    int kt = 0;
    for (; kt < NT - 2; ++kt) ktile(kt & 1, kt, 1, 1, 3);
    ktile(kt & 1, kt, 1, 0, 0); ++kt;   // NT-2: stage NT-1, drain all
    ktile(kt & 1, kt, 0, 0, -1);        // NT-1: compute only

    // ---- epilogue: 2-pass LDS bounce (32 rows x 64 cols per wave per pass) ------
    u16* wb = &sm[0][0] + wid * 2048;   // 4 KB/wave x 8 = 32 KB
    #pragma unroll
    for (int p = 0; p < 2; ++p) {
        #pragma unroll
        for (int m2 = 0; m2 < 2; ++m2) {
            int mi = p * 2 + m2;
            #pragma unroll
            for (int ni = 0; ni < 4; ++ni) {
                float bv = bi[tn + wc * 64 + ni * 16 + (lane & 15)];
                #pragma unroll
                for (int r = 0; r < 4; ++r) {
                    int row = m2 * 16 + (lane >> 4) * 4 + r;
                    int ce  = ni * 16 + (lane & 15);
                    float v = acc[mi][ni][r] + bv;
                    if (RELU) v = fmaxf(v, 0.f);
                    wb[row * 64 + (ce ^ ((row & 7) << 3))] = f2bf(v);
                }
            }
        }
        #pragma unroll
        for (int i = 0; i < 4; ++i) {
            int rr = i * 8 + (lane >> 3);
            bh8_t v = *(const bh8_t*)(wb + rr * 64 + (((lane & 7) * 8) ^ ((rr & 7) << 3)));
            long grow = tm + wr * 64 + p * 32 + rr;
            long gcol = tn + wc * 64 + (lane & 7) * 8;
            *(bh8_t*)(Ce + grow * N + gcol) = v;
        }
    }
}

// ---------------- combine: out[n] = sum_j gate_j * eo[flat_j] ----------------
__global__ __launch_bounds__(256) void k_combine(const u16* __restrict__ eo,
        const int* __restrict__ flat, const float* __restrict__ gates,
        float* __restrict__ out) {
    long n = blockIdx.x;
    int tid = threadIdx.x;
    int f0 = flat[n*2], f1 = flat[n*2+1];
    float g0 = (f0 >= 0) ? gates[n*2]   : 0.f;
    float g1 = (f1 >= 0) ? gates[n*2+1] : 0.f;
    const u16* r0 = eo + (long)(f0 >= 0 ? f0 : 0) * DM;
    const u16* r1 = eo + (long)(f1 >= 0 ? f1 : 0) * DM;
    ushort4 a = *(const ushort4*)(r0 + tid*4);
    ushort4 b = *(const ushort4*)(r1 + tid*4);
    float4 o;
    o.x = g0*bf2f(a.x) + g1*bf2f(b.x);
    o.y = g0*bf2f(a.y) + g1*bf2f(b.y);
    o.z = g0*bf2f(a.z) + g1*bf2f(b.z);
    o.w = g0*bf2f(a.w) + g1*bf2f(b.w);
    *(float4*)(out + n*DM + tid*4) = o;
}

extern "C" void kernel_launch(void* const* d_in, const int* in_sizes, int n_in,
                              void* d_out, int out_size, void* d_ws, size_t ws_size,
                              hipStream_t stream) {
    const float* x    = (const float*)d_in[0];
    const float* gw   = (const float*)d_in[1];
    const float* fc1w = (const float*)d_in[2];
    const float* fc1b = (const float*)d_in[3];
    const float* fc2w = (const float*)d_in[4];
    const float* fc2b = (const float*)d_in[5];
    float* out = (float*)d_out;
    char* ws = (char*)d_ws;

    // ws layout: disp [0,32MB) (aliased by eo), h [32,160MB), w1b [160,224MB),
    // w2t [224,288MB), tail
    u16* disp = (u16*)(ws);
    u16* eo   = disp;                                   // alias: disp dead after GEMM1
    u16* h    = (u16*)(ws + 33554432L);
    u16* w1b  = (u16*)(ws + 33554432L + 134217728L);
    u16* w2t  = (u16*)(ws + 33554432L + 134217728L + 67108864L);
    char* tail = ws + 33554432L + 134217728L + 67108864L + 67108864L;
    int*   topi  = (int*)tail;
    float* gates = (float*)(tail + 65536);
    int*   flat  = (int*)(tail + 131072);

    long n1 = (long)NEXP * HID * DM;

    k_conv_bf16<<<dim3(2048), 256, 0, stream>>>(fc1w, w1b, n1 / 4);
    k_transpose_w2<<<dim3(HID/64, DM/64, NEXP), 256, 0, stream>>>(fc2w, w2t);
    k_gating<<<dim3(NTOK/4), 256, 0, stream>>>(x, gw, topi, gates);
    k_locate<<<dim3(NEXP), 256, 0, stream>>>(topi, flat);
    k_dispatch<<<dim3(NTOK), 256, 0, stream>>>(x, flat, disp);
    k_gemm8<1><<<dim3(HID/BN, CAPS/BM, NEXP), 512, 0, stream>>>(
        disp, w1b, fc1b, h, HID, DM,
        (long)CAPS*DM, (long)HID*DM, (long)HID, (long)CAPS*HID);
    k_gemm8<0><<<dim3(DM/BN, CAPS/BM, NEXP), 512, 0, stream>>>(
        h, w2t, fc2b, eo, DM, HID,
        (long)CAPS*HID, (long)DM*HID, (long)DM, (long)CAPS*DM);
    k_combine<<<dim3(NTOK), 256, 0, stream>>>(eo, flat, gates, out);
}

// Round 13
// 381.526 us; speedup vs baseline: 1.5080x; 1.5080x over previous
//
#include <hip/hip_runtime.h>
#include <hip/hip_bf16.h>
#include <stdint.h>

#define NEXP 8
#define DM   1024
#define HID  4096
#define NTOK 8192
#define CAPS 2048   // expert capacity = K*ceil(N/E) = 2*1024

#define BM 256
#define BN 256
#define BK 64

typedef __attribute__((ext_vector_type(8))) short bh8_t;
typedef __attribute__((ext_vector_type(4))) float f32x4_t;
typedef unsigned short u16;

static __device__ __forceinline__ u16 f2bf(float f) {
    __hip_bfloat16 h = __float2bfloat16(f);
    return __builtin_bit_cast(u16, h);
}
static __device__ __forceinline__ float bf2f(u16 u) {
    unsigned int x = ((unsigned int)u) << 16;
    return __builtin_bit_cast(float, x);
}

#define FENCE asm volatile("" ::: "memory")
#define BAR   do { FENCE; __builtin_amdgcn_s_barrier(); FENCE; } while (0)
#define MFMA(d, a, b) d = __builtin_amdgcn_mfma_f32_16x16x32_bf16(a, b, d, 0, 0, 0)
#define WAITVM(n) do { if ((n) == 4) asm volatile("s_waitcnt vmcnt(4)" ::: "memory"); \
    else if ((n) == 0) asm volatile("s_waitcnt vmcnt(0)" ::: "memory"); } while (0)

// ---------------- fp32 -> bf16 elementwise convert (fc1 weights) ----------------
__global__ __launch_bounds__(256) void k_conv_bf16(const float* __restrict__ in,
                                                   u16* __restrict__ out, long n4) {
    long stride = (long)gridDim.x * 256;
    for (long i = (long)blockIdx.x * 256 + threadIdx.x; i < n4; i += stride) {
        float4 v = ((const float4*)in)[i];
        ushort4 o;
        o.x = f2bf(v.x); o.y = f2bf(v.y); o.z = f2bf(v.z); o.w = f2bf(v.w);
        ((ushort4*)out)[i] = o;
    }
}

// ---------------- fc2 [E,H,D] f32 -> [E,D,H] bf16 transpose (64x64 tiles) --------
__global__ __launch_bounds__(256) void k_transpose_w2(const float* __restrict__ in,
                                                      u16* __restrict__ out) {
    int e = blockIdx.z;
    const float* I = in + (long)e * HID * DM;
    u16* O = out + (long)e * DM * HID;
    __shared__ float t[64][65];
    int h0 = blockIdx.x * 64, d0 = blockIdx.y * 64;
    int tid = threadIdx.x;
    int r = tid >> 4, cw = (tid & 15) * 4;
    #pragma unroll
    for (int i = 0; i < 4; ++i) {
        float4 v = *(const float4*)(I + (long)(h0 + r + 16*i) * DM + d0 + cw);
        t[r + 16*i][cw]     = v.x;
        t[r + 16*i][cw + 1] = v.y;
        t[r + 16*i][cw + 2] = v.z;
        t[r + 16*i][cw + 3] = v.w;
    }
    __syncthreads();
    int dl = tid >> 2, hc = (tid & 3) * 16;
    bh8_t w0, w1;
    #pragma unroll
    for (int j = 0; j < 8; ++j) w0[j] = (short)f2bf(t[hc + j][dl]);
    #pragma unroll
    for (int j = 0; j < 8; ++j) w1[j] = (short)f2bf(t[hc + 8 + j][dl]);
    u16* o = O + (long)(d0 + dl) * HID + h0 + hc;
    *(bh8_t*)o = w0;
    *(bh8_t*)(o + 8) = w1;
}

// ---------------- gating: logits, softmax, top-2, normalized gates ----------------
__global__ __launch_bounds__(256) void k_gating(const float* __restrict__ x,
        const float* __restrict__ gw, int* __restrict__ topi, float* __restrict__ gates) {
    __shared__ float sg[NEXP][DM];   // 32 KB
    int tid = threadIdx.x;
    for (int i = tid; i < NEXP*DM; i += 256) ((float*)sg)[i] = gw[i];
    __syncthreads();
    int lane = tid & 63, w = tid >> 6;
    long n = (long)blockIdx.x * 4 + w;            // one token per wave
    const float* xr = x + n * DM;
    float acc[NEXP] = {};
    for (int i = 0; i < DM/64; ++i) {
        float xv = xr[lane + i*64];
        #pragma unroll
        for (int e = 0; e < NEXP; ++e) acc[e] += xv * sg[e][lane + i*64];
    }
    #pragma unroll
    for (int e = 0; e < NEXP; ++e)
        #pragma unroll
        for (int off = 32; off; off >>= 1) acc[e] += __shfl_xor(acc[e], off);
    if (lane == 0) {
        float mx = acc[0];
        #pragma unroll
        for (int e = 1; e < NEXP; ++e) mx = fmaxf(mx, acc[e]);
        float p[NEXP];
        #pragma unroll
        for (int e = 0; e < NEXP; ++e) p[e] = expf(acc[e] - mx);
        float v0 = p[0]; int i0 = 0;
        #pragma unroll
        for (int e = 1; e < NEXP; ++e) if (p[e] > v0) { v0 = p[e]; i0 = e; }
        float v1 = -1.f; int i1 = 0;
        #pragma unroll
        for (int e = 0; e < NEXP; ++e) if (e != i0 && p[e] > v1) { v1 = p[e]; i1 = e; }
        float tot = v0 + v1;
        topi[n*2]   = i0; topi[n*2+1] = i1;
        gates[n*2]  = v0 / tot; gates[n*2+1] = v1 / tot;
    }
}

// ---- capacity locations: exact sequential cumsum; ONE BLOCK PER EXPERT (8x) ----
// Per-expert columns of the reference's cumsum are independent; block e assigns
// locations only for tokens whose slot-j choice == e, visiting tokens in order.
// offset carries j=0 -> j=1 exactly as the reference's sequential loop.
__global__ __launch_bounds__(256) void k_locate(const int* __restrict__ topi,
                                                int* __restrict__ flat) {
    __shared__ int st[NTOK * 2];    // 64 KB staged topi
    __shared__ int wsum[4];
    int e = blockIdx.x;
    int tid = threadIdx.x, lane = tid & 63, w = tid >> 6;
    int4* st4 = (int4*)st;
    const int4* g4 = (const int4*)topi;
    for (int i = tid; i < NTOK * 2 / 4; i += 256) st4[i] = g4[i];
    __syncthreads();
    const int TPL = NTOK / 256;     // 32 consecutive tokens per thread
    int base = tid * TPL;
    int offset = 0;
    for (int j = 0; j < 2; ++j) {
        int cnt = 0;
        for (int t = 0; t < TPL; ++t) cnt += (st[(base + t) * 2 + j] == e);
        int v = cnt;
        #pragma unroll
        for (int d = 1; d < 64; d <<= 1) {
            int o = __shfl_up(v, d);
            if (lane >= d) v += o;
        }
        if (lane == 63) wsum[w] = v;
        __syncthreads();
        int wb = 0;
        #pragma unroll
        for (int ww = 0; ww < 4; ++ww) if (ww < w) wb += wsum[ww];
        int tot = wsum[0] + wsum[1] + wsum[2] + wsum[3];
        int loc = v - cnt + wb + offset;
        offset += tot;
        for (int t = 0; t < TPL; ++t) {
            int n = base + t;
            if (st[n * 2 + j] == e) {
                flat[n * 2 + j] = (loc < CAPS) ? (e * CAPS + loc) : -1;
                ++loc;
            }
        }
        __syncthreads();
    }
}

// ---------------- dispatch: scatter tokens (bf16) into [E*cap, D] ----------------
__global__ __launch_bounds__(256) void k_dispatch(const float* __restrict__ x,
        const int* __restrict__ flat, u16* __restrict__ disp) {
    long n = blockIdx.x;
    int tid = threadIdx.x;
    float4 v = *(const float4*)(x + n*DM + tid*4);
    ushort4 o; o.x = f2bf(v.x); o.y = f2bf(v.y); o.z = f2bf(v.z); o.w = f2bf(v.w);
    int f0 = flat[n*2], f1 = flat[n*2+1];
    if (f0 >= 0) *(ushort4*)(disp + (long)f0*DM + tid*4) = o;
    if (f1 >= 0) *(ushort4*)(disp + (long)f1*DM + tid*4) = o;
}

// ---------------- staging: one 16KB half-region (128 rows x 64 cols bf16) ----------
// LDS dest linear (base + lane*16); global source pre-swizzled with the inverse of
// the read-side XOR  byte ^= ((row&7)<<4)   (rule #21: both-sides-or-neither).
static __device__ __forceinline__ void stage_half(const u16* __restrict__ g, int ld,
                                                  u16* R, int wid, int lane) {
    int rlo = wid*8 + (lane >> 3);                       // rows 0..63 (q=0), +64 (q=1)
    int cbe = ((lane & 7) ^ ((lane >> 3) & 7)) * 8;      // swizzled source col (elems)
    const u16* s0 = g + (long)rlo * ld + cbe;
    const u16* s1 = g + (long)(rlo + 64) * ld + cbe;
    u16* d0 = R + wid*512 + lane*8;
    u16* d1 = R + 4096 + wid*512 + lane*8;
    __builtin_amdgcn_global_load_lds((const __attribute__((address_space(1))) void*)s0,
        (__attribute__((address_space(3))) void*)d0, 16, 0, 0);
    __builtin_amdgcn_global_load_lds((const __attribute__((address_space(1))) void*)s1,
        (__attribute__((address_space(3))) void*)d1, 16, 0, 0);
}

// ---------------- 256x256 LOW-BARRIER quadrant-uniform bf16 MFMA GEMM ------------
// 2 barriers per K-tile (r9-proven): BAR_mid fences in-tile stages into buffer c;
// BAR_exit after vmcnt handles tile handoff. Compiler schedules freely within the
// two barrier-free regions (r10: SB0 pins removed, neutral).
template<int RELU>
__global__ __launch_bounds__(512, 2)
void k_gemm8(const u16* __restrict__ A, const u16* __restrict__ B,
             const float* __restrict__ bias, u16* __restrict__ C,
             int N, int K, long strA, long strB, long strBias, long strC)
{
    __shared__ u16 sm[2][2][2][8192];   // [buf][A=0/B=1][half][128*64] = 128 KiB

    // T1: XCD-aware bijective remap (nwg % 8 == 0 for our grids)
    int gx = gridDim.x, gy = gridDim.y;
    int nwg = gx * gy * (int)gridDim.z;
    int lin = blockIdx.x + gx * (blockIdx.y + gy * blockIdx.z);
    int qq  = nwg >> 3;
    int swz = (lin & 7) * qq + (lin >> 3);
    int gxy = gx * gy;
    int bz = swz / gxy, rm = swz % gxy, by = rm / gx, bx = rm % gx;

    const float* bi = bias + (long)bz * strBias;
    u16* Ce = C + (long)bz * strC;

    long tm = (long)by * BM, tn = (long)bx * BN;
    const u16* Abase = A + (long)bz * strA + tm * (long)K;
    const u16* Bbase = B + (long)bz * strB + tn * (long)K;

    int tid = threadIdx.x, lane = tid & 63, wid = tid >> 6;
    int wr = wid >> 2, wc = wid & 3;            // 2x4 waves; per-wave 128x64 output

    int frow = lane & 15;
    int fc0 = (((lane >> 4) * 16)      ^ ((lane & 7) << 4)) >> 1;   // kk=0 col (elems)
    int fc1 = ((64 + (lane >> 4) * 16) ^ ((lane & 7) << 4)) >> 1;   // kk=1

    const int NT = K / BK;

    f32x4_t acc[8][4] = {};    // [i*4+mi][j*2+ni]

    auto STG = [&](int buf, int ab, int half, int kt) {
        const u16* g = (ab ? Bbase : Abase) + (long)(half * 128) * K + (long)kt * BK;
        stage_half(g, K, &sm[buf][ab][half][0], wid, lane);
    };
    auto LDA = [&](int c, int half, int mi, int kk) -> bh8_t {
        const u16* p = &sm[c][0][half][0] + (wr * 64 + mi * 16 + frow) * 64 + (kk ? fc1 : fc0);
        return *(const bh8_t*)p;
    };
    auto LDB = [&](int c, int half, int ni, int kk) -> bh8_t {
        const u16* p = &sm[c][1][half][0] + (wc * 32 + ni * 16 + frow) * 64 + (kk ? fc1 : fc0);
        return *(const bh8_t*)p;
    };

    auto ktile = [&](int c, int kt, int s12, int s34, int vmexit) {
        bh8_t a0[4][2], a1[4][2], b0[2][2], b1[2][2];
        // ---- region 1 (ph1+ph2): reads A0,B0,B1; stages (kt+1).B1,(kt+1).A1 -> c^1
        #pragma unroll
        for (int mi = 0; mi < 4; ++mi) { a0[mi][0] = LDA(c, 0, mi, 0); a0[mi][1] = LDA(c, 0, mi, 1); }
        #pragma unroll
        for (int ni = 0; ni < 2; ++ni) { b0[ni][0] = LDB(c, 0, ni, 0); b0[ni][1] = LDB(c, 0, ni, 1); }
        if (s12) STG(c ^ 1, 1, 1, kt + 1);
        __builtin_amdgcn_s_setprio(1);
        #pragma unroll
        for (int mi = 0; mi < 4; ++mi)
            #pragma unroll
            for (int ni = 0; ni < 2; ++ni)
                #pragma unroll
                for (int kk = 0; kk < 2; ++kk) MFMA(acc[mi][ni], a0[mi][kk], b0[ni][kk]);
        __builtin_amdgcn_s_setprio(0);
        #pragma unroll
        for (int ni = 0; ni < 2; ++ni) { b1[ni][0] = LDB(c, 1, ni, 0); b1[ni][1] = LDB(c, 1, ni, 1); }
        if (s12) STG(c ^ 1, 0, 1, kt + 1);
        __builtin_amdgcn_s_setprio(1);
        #pragma unroll
        for (int mi = 0; mi < 4; ++mi)
            #pragma unroll
            for (int ni = 0; ni < 2; ++ni)
                #pragma unroll
                for (int kk = 0; kk < 2; ++kk) MFMA(acc[mi][2 + ni], a0[mi][kk], b1[ni][kk]);
        __builtin_amdgcn_s_setprio(0);
        BAR;   // <-- in-tile hazard fence: c.A0/c.B0 reads all consumed above
        // ---- region 2 (ph3+ph4): reads A1; stages (kt+2).A0,(kt+2).B0 -> c
        #pragma unroll
        for (int mi = 0; mi < 4; ++mi) { a1[mi][0] = LDA(c, 1, mi, 0); a1[mi][1] = LDA(c, 1, mi, 1); }
        if (s34) STG(c, 0, 0, kt + 2);
        __builtin_amdgcn_s_setprio(1);
        #pragma unroll
        for (int mi = 0; mi < 4; ++mi)
            #pragma unroll
            for (int ni = 0; ni < 2; ++ni)
                #pragma unroll
                for (int kk = 0; kk < 2; ++kk) MFMA(acc[4 + mi][ni], a1[mi][kk], b0[ni][kk]);
        __builtin_amdgcn_s_setprio(0);
        if (s34) STG(c, 1, 0, kt + 2);
        __builtin_amdgcn_s_setprio(1);
        #pragma unroll
        for (int mi = 0; mi < 4; ++mi)
            #pragma unroll
            for (int ni = 0; ni < 2; ++ni)
                #pragma unroll
                for (int kk = 0; kk < 2; ++kk) MFMA(acc[4 + mi][2 + ni], a1[mi][kk], b1[ni][kk]);
        __builtin_amdgcn_s_setprio(0);
        WAITVM(vmexit);
        BAR;   // <-- tile handoff
    };

    // prologue: kt0 fully (A0,B0,B1,A1), kt1 A0+B0; vmcnt(4) forces kt0, leaves
    // [kt1.A0, kt1.B0] in flight = steady-state entry invariant.
    STG(0, 0, 0, 0); STG(0, 1, 0, 0); STG(0, 1, 1, 0); STG(0, 0, 1, 0);
    STG(1, 0, 0, 1); STG(1, 1, 0, 1);
    asm volatile("s_waitcnt vmcnt(4)" ::: "memory");
    BAR;

    int kt = 0;
    for (; kt < NT - 2; ++kt) ktile(kt & 1, kt, 1, 1, 4);
    ktile(kt & 1, kt, 1, 0, 0); ++kt;   // NT-2: drain all (incl. NT-1 stages)
    ktile(kt & 1, kt, 0, 0, -1);        // NT-1: compute only

    // ---- epilogue: acc -> LDS bounce (swizzled) -> coalesced 16B global stores ----
    u16* wb = &sm[0][0][0][0] + wid * 8192;
    #pragma unroll
    for (int mi = 0; mi < 8; ++mi)
        #pragma unroll
        for (int ni = 0; ni < 4; ++ni) {
            float bv = bi[tn + (ni >> 1) * 128 + wc * 32 + (ni & 1) * 16 + (lane & 15)];
            #pragma unroll
            for (int r = 0; r < 4; ++r) {
                int row = mi * 16 + (lane >> 4) * 4 + r;
                int ce  = ni * 16 + (lane & 15);
                float v = acc[mi][ni][r] + bv;
                if (RELU) v = fmaxf(v, 0.f);
                wb[row * 64 + (ce ^ ((row & 7) << 3))] = f2bf(v);
            }
        }
    __syncthreads();
    long crow0 = tm + wr * 64;
    long ccol  = tn + wc * 32 + (lane & 3) * 8 + ((lane >> 2) & 1) * 128;
    #pragma unroll
    for (int i = 0; i < 16; ++i) {
        int rr = i * 8 + (lane >> 3);
        bh8_t v = *(const bh8_t*)(wb + rr * 64 + (((lane & 7) * 8) ^ ((rr & 7) << 3)));
        long grow = crow0 + (rr & 63) + (rr >> 6) * 128;
        *(bh8_t*)(Ce + grow * N + ccol) = v;
    }
}

// ---------------- combine: out[n] = sum_j gate_j * eo[flat_j] ----------------
__global__ __launch_bounds__(256) void k_combine(const u16* __restrict__ eo,
        const int* __restrict__ flat, const float* __restrict__ gates,
        float* __restrict__ out) {
    long n = blockIdx.x;
    int tid = threadIdx.x;
    int f0 = flat[n*2], f1 = flat[n*2+1];
    float g0 = (f0 >= 0) ? gates[n*2]   : 0.f;
    float g1 = (f1 >= 0) ? gates[n*2+1] : 0.f;
    const u16* r0 = eo + (long)(f0 >= 0 ? f0 : 0) * DM;
    const u16* r1 = eo + (long)(f1 >= 0 ? f1 : 0) * DM;
    ushort4 a = *(const ushort4*)(r0 + tid*4);
    ushort4 b = *(const ushort4*)(r1 + tid*4);
    float4 o;
    o.x = g0*bf2f(a.x) + g1*bf2f(b.x);
    o.y = g0*bf2f(a.y) + g1*bf2f(b.y);
    o.z = g0*bf2f(a.z) + g1*bf2f(b.z);
    o.w = g0*bf2f(a.w) + g1*bf2f(b.w);
    *(float4*)(out + n*DM + tid*4) = o;
}

extern "C" void kernel_launch(void* const* d_in, const int* in_sizes, int n_in,
                              void* d_out, int out_size, void* d_ws, size_t ws_size,
                              hipStream_t stream) {
    const float* x    = (const float*)d_in[0];
    const float* gw   = (const float*)d_in[1];
    const float* fc1w = (const float*)d_in[2];
    const float* fc1b = (const float*)d_in[3];
    const float* fc2w = (const float*)d_in[4];
    const float* fc2b = (const float*)d_in[5];
    float* out = (float*)d_out;
    char* ws = (char*)d_ws;

    // ws layout: disp [0,32MB) (aliased by eo), h [32,160MB), w1b [160,224MB),
    // w2t [224,288MB), tail
    u16* disp = (u16*)(ws);
    u16* eo   = disp;                                   // alias: disp dead after GEMM1
    u16* h    = (u16*)(ws + 33554432L);
    u16* w1b  = (u16*)(ws + 33554432L + 134217728L);
    u16* w2t  = (u16*)(ws + 33554432L + 134217728L + 67108864L);
    char* tail = ws + 33554432L + 134217728L + 67108864L + 67108864L;
    int*   topi  = (int*)tail;
    float* gates = (float*)(tail + 65536);
    int*   flat  = (int*)(tail + 131072);

    long n1 = (long)NEXP * HID * DM;

    k_conv_bf16<<<dim3(2048), 256, 0, stream>>>(fc1w, w1b, n1 / 4);
    k_transpose_w2<<<dim3(HID/64, DM/64, NEXP), 256, 0, stream>>>(fc2w, w2t);
    k_gating<<<dim3(NTOK/4), 256, 0, stream>>>(x, gw, topi, gates);
    k_locate<<<dim3(NEXP), 256, 0, stream>>>(topi, flat);
    k_dispatch<<<dim3(NTOK), 256, 0, stream>>>(x, flat, disp);
    k_gemm8<1><<<dim3(HID/BN, CAPS/BM, NEXP), 512, 0, stream>>>(
        disp, w1b, fc1b, h, HID, DM,
        (long)CAPS*DM, (long)HID*DM, (long)HID, (long)CAPS*HID);
    k_gemm8<0><<<dim3(DM/BN, CAPS/BM, NEXP), 512, 0, stream>>>(
        h, w2t, fc2b, eo, DM, HID,
        (long)CAPS*HID, (long)DM*HID, (long)DM, (long)CAPS*DM);
    k_combine<<<dim3(NTOK), 256, 0, stream>>>(eo, flat, gates, out);
}